// Round 1
// baseline (83.895 us; speedup 1.0000x reference)
//
#include <hip/hip_runtime.h>

typedef __attribute__((ext_vector_type(8))) short bf16x8;
typedef __attribute__((ext_vector_type(4))) float f32x4;

__device__ __forceinline__ unsigned int f2bf(float f) {
    union { float f; unsigned int u; } v; v.f = f;
    unsigned int u = v.u;
    u += 0x7FFFu + ((u >> 16) & 1u);   // round-to-nearest-even
    return u >> 16;
}

// Pack lin1_W [256][256] f32 (row-major, W[k][n]) into bf16 MFMA-B-fragment order:
// 16B unit index tid = (kt*16 + f)*64 + lane holds
//   { W[kt*32 + (lane>>4)*8 + j][f*16 + (lane&15)] : j = 0..7 }
__global__ void pack_w_kernel(const float* __restrict__ W, unsigned short* __restrict__ P) {
    int tid = blockIdx.x * blockDim.x + threadIdx.x;
    if (tid >= 8192) return;
    int kt   = tid >> 10;
    int f    = (tid >> 6) & 15;
    int lane = tid & 63;
    int k0  = kt * 32 + (lane >> 4) * 8;
    int col = f * 16 + (lane & 15);
    bf16x8 v;
    #pragma unroll
    for (int j = 0; j < 8; ++j)
        v[j] = (short)f2bf(W[(k0 + j) * 256 + col]);
    ((bf16x8*)P)[tid] = v;
}

__global__ __launch_bounds__(256)
void fused_kernel(const float* __restrict__ x,
                  const int* __restrict__ samples,
                  const unsigned short* __restrict__ Wp,
                  const float* __restrict__ b1,
                  const float* __restrict__ w2,
                  const float* __restrict__ b2,
                  float* __restrict__ out, int S)
{
    // z tile: 64 rows x 256 cols bf16, row stride 264 (pad 8) -> A-frag ds_read_b128 is 2-way (free)
    __shared__ unsigned short zt[64][264];   // 33,792 B
    __shared__ unsigned short wt[8192];      // 16 KiB W chunk (one K-tile, fragment-linear)

    const int tid  = threadIdx.x;
    const int lane = tid & 63;
    const int wave = tid >> 6;
    const int row0 = blockIdx.x * 64;
    const int cl   = lane & 15;
    const int hi   = lane >> 4;

    // ---- stage z tile: one wave stages a full 1 KiB row per iteration (coalesced float4) ----
    for (int rr = wave; rr < 64; rr += 4) {
        int r  = row0 + rr;
        int rc = r < S ? r : S - 1;            // clamp tail rows; stores are masked later
        int a = samples[2 * rc];
        int b = samples[2 * rc + 1];
        f32x4 va = ((const f32x4*)x)[a * 64 + lane];
        f32x4 vb = ((const f32x4*)x)[b * 64 + lane];
        unsigned int lo = f2bf(va[0] * vb[0]) | (f2bf(va[1] * vb[1]) << 16);
        unsigned int h2 = f2bf(va[2] * vb[2]) | (f2bf(va[3] * vb[3]) << 16);
        uint2 u; u.x = lo; u.y = h2;
        *(uint2*)&zt[rr][lane * 4] = u;
    }

    // bias registers: lane's D columns are c = f*16 + cl
    float b1r[16];
    #pragma unroll
    for (int f = 0; f < 16; ++f) b1r[f] = b1[f * 16 + cl];

    f32x4 acc[16];
    #pragma unroll
    for (int f = 0; f < 16; ++f) acc[f] = (f32x4){0.f, 0.f, 0.f, 0.f};

    const int arow = wave * 16 + cl;   // this lane's A row within the block tile

    for (int kt = 0; kt < 8; ++kt) {
        __syncthreads();               // protect wt from previous iteration's readers
        // linear 16 KiB copy, coalesced, fragment-order so B reads below are conflict-free
        const bf16x8* src  = (const bf16x8*)(Wp + (size_t)kt * 8192);
        bf16x8*       dstv = (bf16x8*)wt;
        #pragma unroll
        for (int i = 0; i < 4; ++i) dstv[i * 256 + tid] = src[i * 256 + tid];
        __syncthreads();

        // A fragment: lane holds z[arow][kt*32 + hi*8 .. +8]  (16B aligned: 528*row + 64*kt + 16*hi)
        bf16x8 af = *(const bf16x8*)&zt[arow][kt * 32 + hi * 8];
        const bf16x8* wb = (const bf16x8*)wt;
        #pragma unroll
        for (int f = 0; f < 16; ++f) {
            bf16x8 bfr = wb[f * 64 + lane];
            acc[f] = __builtin_amdgcn_mfma_f32_16x16x32_bf16(af, bfr, acc[f], 0, 0, 0);
        }
    }

    // ---- epilogue: bias + ReLU, then [16x256]x[256x2] via VALU + 16-lane shuffle reduce ----
    float p0[4] = {0.f, 0.f, 0.f, 0.f};
    float p1[4] = {0.f, 0.f, 0.f, 0.f};
    #pragma unroll
    for (int f = 0; f < 16; ++f) {
        int c = f * 16 + cl;
        float2 lw = ((const float2*)w2)[c];
        #pragma unroll
        for (int q = 0; q < 4; ++q) {
            float h = fmaxf(acc[f][q] + b1r[f], 0.f);
            p0[q] += h * lw.x;
            p1[q] += h * lw.y;
        }
    }
    #pragma unroll
    for (int m = 1; m < 16; m <<= 1) {
        #pragma unroll
        for (int q = 0; q < 4; ++q) {
            p0[q] += __shfl_xor(p0[q], m, 64);
            p1[q] += __shfl_xor(p1[q], m, 64);
        }
    }
    // lanes cl=0..7 of each 16-lane group write 8 consecutive floats (4 rows x 2 cols)
    if (cl < 8) {
        int q = cl >> 1, j = cl & 1;
        int r = row0 + wave * 16 + hi * 4 + q;
        if (r < S) {
            float v = (j == 0 ? p0[q] : p1[q]) + b2[j];
            out[r * 2 + j] = v;
        }
    }
}

extern "C" void kernel_launch(void* const* d_in, const int* in_sizes, int n_in,
                              void* d_out, int out_size, void* d_ws, size_t ws_size,
                              hipStream_t stream) {
    // setup_inputs order:
    // 0 x_feature, 1 edge_index(unused), 2 samples, 3 W1(u), 4 b1(u), 5 W2(u), 6 b2(u),
    // 7 lin1_W, 8 lin1_b, 9 lin2_W, 10 lin2_b
    const float* x       = (const float*)d_in[0];
    const int*   samples = (const int*)d_in[2];
    const float* lin1_W  = (const float*)d_in[7];
    const float* lin1_b  = (const float*)d_in[8];
    const float* lin2_W  = (const float*)d_in[9];
    const float* lin2_b  = (const float*)d_in[10];
    float* out = (float*)d_out;

    unsigned short* Wp = (unsigned short*)d_ws;   // 8192 * 16B = 128 KiB packed lin1_W
    const int S = in_sizes[2] / 2;                // 100000 sample pairs

    pack_w_kernel<<<32, 256, 0, stream>>>(lin1_W, Wp);

    const int nblk = (S + 63) / 64;
    fused_kernel<<<nblk, 256, 0, stream>>>(x, samples, Wp, lin1_b, lin2_W, lin2_b, out, S);
}

// Round 2
// 63.197 us; speedup vs baseline: 1.3275x; 1.3275x over previous
//
#include <hip/hip_runtime.h>

typedef __attribute__((ext_vector_type(8))) short bf16x8;
typedef __attribute__((ext_vector_type(4))) float f32x4;

__device__ __forceinline__ unsigned int f2bf(float f) {
    union { float f; unsigned int u; } v; v.f = f;
    unsigned int u = v.u;
    u += 0x7FFFu + ((u >> 16) & 1u);   // round-to-nearest-even
    return u >> 16;
}

// Pack lin1_W [256][256] f32 (row-major, W[k][n]) into bf16 MFMA-B-fragment order:
// 16B unit index tid = (kt*16 + f)*64 + lane holds
//   { W[kt*32 + (lane>>4)*8 + j][f*16 + (lane&15)] : j = 0..7 }
__global__ void pack_w_kernel(const float* __restrict__ W, unsigned short* __restrict__ P) {
    int tid = blockIdx.x * blockDim.x + threadIdx.x;
    if (tid >= 8192) return;
    int kt   = tid >> 10;
    int f    = (tid >> 6) & 15;
    int lane = tid & 63;
    int k0  = kt * 32 + (lane >> 4) * 8;
    int col = f * 16 + (lane & 15);
    bf16x8 v;
    #pragma unroll
    for (int j = 0; j < 8; ++j)
        v[j] = (short)f2bf(W[(k0 + j) * 256 + col]);
    ((bf16x8*)P)[tid] = v;
}

__global__ __launch_bounds__(256, 4)
void fused_kernel(const float* __restrict__ x,
                  const int* __restrict__ samples,
                  const unsigned short* __restrict__ Wp,
                  const float* __restrict__ b1,
                  const float* __restrict__ w2,
                  const float* __restrict__ b2,
                  float* __restrict__ out, int S)
{
    // Per-wave PRIVATE 16-row z tiles (bf16, pad 8) -> no __syncthreads anywhere.
    __shared__ unsigned short zt[4][16][264];   // 33,792 B -> 4 blocks/CU

    const int tid  = threadIdx.x;
    const int lane = tid & 63;
    const int wave = tid >> 6;
    const int row0 = blockIdx.x * 64 + wave * 16;   // this wave's first output row
    const int cl   = lane & 15;
    const int hi   = lane >> 4;

    // ---- load this wave's 32 sample indices once (coalesced, lanes 0..31) ----
    int sidx;
    {
        int i    = row0 * 2 + (lane & 31);
        int imax = 2 * S - 1;
        sidx = samples[i < imax ? i : imax];
    }

    // ---- gather + multiply + bf16-pack into private LDS slice (unroll x2 for MLP) ----
    #pragma unroll
    for (int rr = 0; rr < 16; rr += 2) {
        int a0 = __shfl(sidx, 2 * rr,     64);
        int b0 = __shfl(sidx, 2 * rr + 1, 64);
        int a1 = __shfl(sidx, 2 * rr + 2, 64);
        int b1i= __shfl(sidx, 2 * rr + 3, 64);
        f32x4 va0 = ((const f32x4*)x)[(size_t)a0 * 64 + lane];
        f32x4 vb0 = ((const f32x4*)x)[(size_t)b0 * 64 + lane];
        f32x4 va1 = ((const f32x4*)x)[(size_t)a1 * 64 + lane];
        f32x4 vb1 = ((const f32x4*)x)[(size_t)b1i * 64 + lane];
        uint2 u0, u1;
        u0.x = f2bf(va0[0] * vb0[0]) | (f2bf(va0[1] * vb0[1]) << 16);
        u0.y = f2bf(va0[2] * vb0[2]) | (f2bf(va0[3] * vb0[3]) << 16);
        u1.x = f2bf(va1[0] * vb1[0]) | (f2bf(va1[1] * vb1[1]) << 16);
        u1.y = f2bf(va1[2] * vb1[2]) | (f2bf(va1[3] * vb1[3]) << 16);
        *(uint2*)&zt[wave][rr][lane * 4]     = u0;
        *(uint2*)&zt[wave][rr + 1][lane * 4] = u1;
    }
    // no barrier: this wave wrote and will read only zt[wave] (compiler orders via lgkmcnt)

    // bias registers: lane's D columns are c = f*16 + cl
    float b1r[16];
    #pragma unroll
    for (int f = 0; f < 16; ++f) b1r[f] = b1[f * 16 + cl];

    f32x4 acc[16];
    #pragma unroll
    for (int f = 0; f < 16; ++f) acc[f] = (f32x4){0.f, 0.f, 0.f, 0.f};

    // ---- K loop: A-frag from private LDS, B-frags straight from L2-resident Wp ----
    const bf16x8* wg = (const bf16x8*)Wp;
    for (int kt = 0; kt < 8; ++kt) {
        bf16x8 af = *(const bf16x8*)&zt[wave][cl][kt * 32 + hi * 8];
        const bf16x8* wk = wg + (size_t)kt * 1024 + lane;
        #pragma unroll
        for (int f = 0; f < 16; ++f) {
            bf16x8 bfr = wk[f * 64];
            acc[f] = __builtin_amdgcn_mfma_f32_16x16x32_bf16(af, bfr, acc[f], 0, 0, 0);
        }
    }

    // ---- epilogue: bias + ReLU, then [16x256]x[256x2] via VALU + 16-lane shuffle reduce ----
    float p0[4] = {0.f, 0.f, 0.f, 0.f};
    float p1[4] = {0.f, 0.f, 0.f, 0.f};
    #pragma unroll
    for (int f = 0; f < 16; ++f) {
        int c = f * 16 + cl;
        float2 lw = ((const float2*)w2)[c];
        #pragma unroll
        for (int q = 0; q < 4; ++q) {
            float h = fmaxf(acc[f][q] + b1r[f], 0.f);
            p0[q] += h * lw.x;
            p1[q] += h * lw.y;
        }
    }
    #pragma unroll
    for (int m = 1; m < 16; m <<= 1) {
        #pragma unroll
        for (int q = 0; q < 4; ++q) {
            p0[q] += __shfl_xor(p0[q], m, 64);
            p1[q] += __shfl_xor(p1[q], m, 64);
        }
    }
    // lanes cl=0..7 of each 16-lane group write 8 consecutive floats (4 rows x 2 cols)
    if (cl < 8) {
        int q = cl >> 1, j = cl & 1;
        int r = row0 + hi * 4 + q;
        if (r < S) {
            float v = (j == 0 ? p0[q] : p1[q]) + b2[j];
            out[r * 2 + j] = v;
        }
    }
}

extern "C" void kernel_launch(void* const* d_in, const int* in_sizes, int n_in,
                              void* d_out, int out_size, void* d_ws, size_t ws_size,
                              hipStream_t stream) {
    // setup_inputs order:
    // 0 x_feature, 1 edge_index(unused), 2 samples, 3 W1(u), 4 b1(u), 5 W2(u), 6 b2(u),
    // 7 lin1_W, 8 lin1_b, 9 lin2_W, 10 lin2_b
    const float* x       = (const float*)d_in[0];
    const int*   samples = (const int*)d_in[2];
    const float* lin1_W  = (const float*)d_in[7];
    const float* lin1_b  = (const float*)d_in[8];
    const float* lin2_W  = (const float*)d_in[9];
    const float* lin2_b  = (const float*)d_in[10];
    float* out = (float*)d_out;

    unsigned short* Wp = (unsigned short*)d_ws;   // 8192 * 16B = 128 KiB packed lin1_W
    const int S = in_sizes[2] / 2;                // 100000 sample pairs

    pack_w_kernel<<<32, 256, 0, stream>>>(lin1_W, Wp);

    const int nblk = (S + 63) / 64;
    fused_kernel<<<nblk, 256, 0, stream>>>(x, samples, Wp, lin1_b, lin2_W, lin2_b, out, S);
}

// Round 3
// 62.622 us; speedup vs baseline: 1.3397x; 1.0092x over previous
//
#include <hip/hip_runtime.h>

typedef __attribute__((ext_vector_type(8))) short bf16x8;
typedef __attribute__((ext_vector_type(4))) float f32x4;

__device__ __forceinline__ unsigned int f2bf(float f) {
    union { float f; unsigned int u; } v; v.f = f;
    unsigned int u = v.u;
    u += 0x7FFFu + ((u >> 16) & 1u);   // round-to-nearest-even
    return u >> 16;
}

// Pack lin1_W [256][256] f32 (row-major, W[k][n]) into bf16 MFMA-B-fragment order,
// F-MAJOR: 16B unit index tid = (f*8 + kt)*64 + lane holds
//   { W[kt*32 + (lane>>4)*8 + j][f*16 + (lane&15)] : j = 0..7 }
__global__ void pack_w_kernel(const float* __restrict__ W, unsigned short* __restrict__ P) {
    int tid = blockIdx.x * blockDim.x + threadIdx.x;
    if (tid >= 8192) return;
    int f    = tid >> 9;
    int kt   = (tid >> 6) & 7;
    int lane = tid & 63;
    int k0  = kt * 32 + (lane >> 4) * 8;
    int col = f * 16 + (lane & 15);
    bf16x8 v;
    #pragma unroll
    for (int j = 0; j < 8; ++j)
        v[j] = (short)f2bf(W[(k0 + j) * 256 + col]);
    ((bf16x8*)P)[tid] = v;
}

__global__ __launch_bounds__(256, 4)
void fused_kernel(const float* __restrict__ x,
                  const int* __restrict__ samples,
                  const unsigned short* __restrict__ Wp,
                  const float* __restrict__ b1,
                  const float* __restrict__ w2,
                  const float* __restrict__ b2,
                  float* __restrict__ out, int S)
{
    // Per-wave PRIVATE 16-row z tiles (bf16, pad 8) -> no __syncthreads anywhere.
    __shared__ unsigned short zt[4][16][264];   // 33,792 B -> 4 blocks/CU

    const int tid  = threadIdx.x;
    const int lane = tid & 63;
    const int wave = tid >> 6;
    const int row0 = blockIdx.x * 64 + wave * 16;   // this wave's first output row
    const int cl   = lane & 15;
    const int hi   = lane >> 4;

    // ---- load this wave's 32 sample indices once (coalesced, lanes 0..31) ----
    int sidx;
    {
        int i    = row0 * 2 + (lane & 31);
        int imax = 2 * S - 1;
        sidx = samples[i < imax ? i : imax];
    }

    // ---- gather + multiply + bf16-pack into private LDS slice; 8 loads in flight ----
    #pragma unroll
    for (int g = 0; g < 4; ++g) {
        f32x4 va[4], vb[4];
        #pragma unroll
        for (int r = 0; r < 4; ++r) {
            int a = __shfl(sidx, (g * 4 + r) * 2,     64);
            int b = __shfl(sidx, (g * 4 + r) * 2 + 1, 64);
            va[r] = ((const f32x4*)x)[(size_t)a * 64 + lane];
            vb[r] = ((const f32x4*)x)[(size_t)b * 64 + lane];
        }
        #pragma unroll
        for (int r = 0; r < 4; ++r) {
            uint2 u;
            u.x = f2bf(va[r][0] * vb[r][0]) | (f2bf(va[r][1] * vb[r][1]) << 16);
            u.y = f2bf(va[r][2] * vb[r][2]) | (f2bf(va[r][3] * vb[r][3]) << 16);
            *(uint2*)&zt[wave][g * 4 + r][lane * 4] = u;
        }
    }
    // no barrier: this wave wrote and will read only zt[wave]

    // ---- hoist A-fragments: lane holds z[cl][kt*32 + hi*8 .. +8] for kt=0..7 ----
    bf16x8 af[8];
    #pragma unroll
    for (int kt = 0; kt < 8; ++kt)
        af[kt] = *(const bf16x8*)&zt[wave][cl][kt * 32 + hi * 8];

    // ---- f-major K loop with fused epilogue and B double-buffer ----
    const bf16x8* wg = (const bf16x8*)Wp + lane;
    float p0[4] = {0.f, 0.f, 0.f, 0.f};
    float p1[4] = {0.f, 0.f, 0.f, 0.f};

    bf16x8 bc[8];
    #pragma unroll
    for (int kt = 0; kt < 8; ++kt) bc[kt] = wg[kt * 64];

    #pragma unroll
    for (int f = 0; f < 16; ++f) {
        bf16x8 bn[8];
        if (f < 15) {
            #pragma unroll
            for (int kt = 0; kt < 8; ++kt) bn[kt] = wg[(f + 1) * 512 + kt * 64];
        }
        f32x4 a4 = (f32x4){0.f, 0.f, 0.f, 0.f};
        #pragma unroll
        for (int kt = 0; kt < 8; ++kt)
            a4 = __builtin_amdgcn_mfma_f32_16x16x32_bf16(af[kt], bc[kt], a4, 0, 0, 0);

        float  b1v = b1[f * 16 + cl];
        float2 lw  = ((const float2*)w2)[f * 16 + cl];
        #pragma unroll
        for (int q = 0; q < 4; ++q) {
            float h = fmaxf(a4[q] + b1v, 0.f);
            p0[q] += h * lw.x;
            p1[q] += h * lw.y;
        }
        #pragma unroll
        for (int kt = 0; kt < 8; ++kt) bc[kt] = bn[kt];
    }

    // ---- 16-lane shuffle reduce of the [16x2] partials ----
    #pragma unroll
    for (int m = 1; m < 16; m <<= 1) {
        #pragma unroll
        for (int q = 0; q < 4; ++q) {
            p0[q] += __shfl_xor(p0[q], m, 64);
            p1[q] += __shfl_xor(p1[q], m, 64);
        }
    }
    // lanes cl=0..7 of each 16-lane group write 8 consecutive floats (4 rows x 2 cols)
    if (cl < 8) {
        int q = cl >> 1, j = cl & 1;
        int r = row0 + hi * 4 + q;
        if (r < S) {
            float v = (j == 0 ? p0[q] : p1[q]) + b2[j];
            out[r * 2 + j] = v;
        }
    }
}

extern "C" void kernel_launch(void* const* d_in, const int* in_sizes, int n_in,
                              void* d_out, int out_size, void* d_ws, size_t ws_size,
                              hipStream_t stream) {
    // setup_inputs order:
    // 0 x_feature, 1 edge_index(unused), 2 samples, 3 W1(u), 4 b1(u), 5 W2(u), 6 b2(u),
    // 7 lin1_W, 8 lin1_b, 9 lin2_W, 10 lin2_b
    const float* x       = (const float*)d_in[0];
    const int*   samples = (const int*)d_in[2];
    const float* lin1_W  = (const float*)d_in[7];
    const float* lin1_b  = (const float*)d_in[8];
    const float* lin2_W  = (const float*)d_in[9];
    const float* lin2_b  = (const float*)d_in[10];
    float* out = (float*)d_out;

    unsigned short* Wp = (unsigned short*)d_ws;   // 8192 * 16B = 128 KiB packed lin1_W
    const int S = in_sizes[2] / 2;                // 100000 sample pairs

    pack_w_kernel<<<32, 256, 0, stream>>>(lin1_W, Wp);

    const int nblk = (S + 63) / 64;
    fused_kernel<<<nblk, 256, 0, stream>>>(x, samples, Wp, lin1_b, lin2_W, lin2_b, out, S);
}